// Round 20
// baseline (212.349 us; speedup 1.0000x reference)
//
#include <hip/hip_runtime.h>
#include <math.h>

#define SEQ   2048
#define HD    128
#define KVB   64
#define NT    (SEQ / KVB)
// (1/sqrt(128)) * log2(e)
#define SCALE_L2E 0.12753242193263556f

typedef __bf16 bf16_t;
typedef __bf16 bf16x2 __attribute__((ext_vector_type(2)));
typedef __bf16 bf16x4 __attribute__((ext_vector_type(4)));
typedef __bf16 bf16x8 __attribute__((ext_vector_type(8)));
typedef float  f32x4  __attribute__((ext_vector_type(4)));

// direct global->LDS DMA, 16B per lane (global addr per-lane, LDS base wave-uniform)
__device__ __forceinline__ void gl_lds16(const void* g, void* l) {
  __builtin_amdgcn_global_load_lds(
      (const __attribute__((address_space(1))) unsigned int*)g,
      (__attribute__((address_space(3))) unsigned int*)l, 16, 0, 0);
}

// ---------------------------------------------------------------------------
// Fused prepass (single launch):
//   blocks [0,2048):    K LDS-image  img[(r*256+c*2)^((r&7)<<4)] = bf16(K)
//   blocks [2048,4096): V^T LDS-image with 16x16-PV slot permutation baked in:
//                       slot s = [m(1)|hi4(2)|j2(1)|j1(2)] holds
//                       k = (s&32) | ((s>>2&1)<<4) | ((s>>3&3)<<2) | (s&3)
//   blocks [4096,6144): packed mask MT2[(k>>6)*32+(k&31)][q] =
//                       bf16x2(M[q][k]*s, M[q][k+32]*s)
// ---------------------------------------------------------------------------
__global__ __launch_bounds__(256)
void prep_all(const float* __restrict__ k, const float* __restrict__ v,
              const float* __restrict__ m, char* __restrict__ kimg,
              char* __restrict__ vimg, bf16x2* __restrict__ mt2) {
  __shared__ float vtile[KVB][HD + 4];
  __shared__ float mtile[32][65];
  const int tid = threadIdx.x;
  const int bx  = blockIdx.x;

  if (bx < 2048) {
    // ---- K image (unchanged layout) ----
    const int bt = bx;
    const float* src = k + (size_t)bt * KVB * HD;
    char* dst = kimg + (size_t)bt * 16384;
#pragma unroll
    for (int i = 0; i < 8; ++i) {
      const int g = tid + i * 256;
      const int r = g >> 5, c4 = g & 31;
      float4 a = *(const float4*)(src + (size_t)r * HD + c4 * 4);
      const int o = (r * 256 + c4 * 8) ^ ((r & 7) << 4);
      *(bf16x4*)(dst + o) = bf16x4{(bf16_t)a.x, (bf16_t)a.y, (bf16_t)a.z, (bf16_t)a.w};
    }
  } else if (bx < 4096) {
    // ---- V^T image with 16x16-PV permutation ----
    const int bt = bx - 2048;
    const float* src = v + (size_t)bt * KVB * HD;
    char* dst = vimg + (size_t)bt * 16384;
#pragma unroll
    for (int i = 0; i < 8; ++i) {
      const int g = tid + i * 256;
      const int r = g >> 5, c4 = g & 31;
      float4 a = *(const float4*)(src + (size_t)r * HD + c4 * 4);
      vtile[r][c4 * 4 + 0] = a.x; vtile[r][c4 * 4 + 1] = a.y;
      vtile[r][c4 * 4 + 2] = a.z; vtile[r][c4 * 4 + 3] = a.w;
    }
    __syncthreads();
#pragma unroll
    for (int i = 0; i < 8; ++i) {
      const int g = tid + i * 256;          // 8B image chunk index
      const int o = g * 8;
      const int d = o >> 7;
      const int inner = (o & 127) ^ ((d & 7) << 4);
      const int s0 = inner >> 1;            // slot base (multiple of 4)
      bf16x4 w;
#pragma unroll
      for (int e = 0; e < 4; ++e) {
        const int s  = s0 + e;
        const int kk = (s & 32) | (((s >> 2) & 1) << 4) |
                       (((s >> 3) & 3) << 2) | (s & 3);
        w[e] = (bf16_t)vtile[kk][d];
      }
      *(bf16x4*)(dst + o) = w;
    }
  } else {
    // ---- packed mask (unchanged) ----
    const int mid = bx - 4096;           // 0..2047
    const int k0  = (mid & 31) * 64;
    const int q0  = (mid >> 5) * 32;
#pragma unroll
    for (int i = 0; i < 2; ++i) {
      const int ix = tid + i * 256;
      const int qr = ix >> 4, c4 = ix & 15;
      float4 a = *(const float4*)(m + (size_t)(q0 + qr) * SEQ + k0 + c4 * 4);
      mtile[qr][c4 * 4 + 0] = a.x; mtile[qr][c4 * 4 + 1] = a.y;
      mtile[qr][c4 * 4 + 2] = a.z; mtile[qr][c4 * 4 + 3] = a.w;
    }
    __syncthreads();
#pragma unroll
    for (int i = 0; i < 4; ++i) {
      const int ix = tid + i * 256;
      const int kl = ix >> 5, qq = ix & 31;
      mt2[(size_t)((mid & 31) * 32 + kl) * SEQ + q0 + qq] =
          bf16x2{(bf16_t)(mtile[qq][kl] * SCALE_L2E),
                 (bf16_t)(mtile[qq][kl + 32] * SCALE_L2E)};
    }
  }
}

// ---------------------------------------------------------------------------
// Main v11: 16x16x32-MFMA occupancy rewrite. 8 waves x 16 q-rows = 128 q-rows
// per 512-thread block; per-wave register state ~halved (ot 8xf32x4, sacc
// 4xf32x4, qf 4x4, p 16, lsum 4) so 4 waves/SIMD fit under launch_bounds
// (512,4) cap=128. Same DMA-image pipeline as v8/v10: K+V double-buffered,
// ONE barrier/iter, no max-tracking, deferred l, no cross-lane in loop.
// Fragment maps: R1-verified 16x16x32 conventions (A/B row/col=lane&15,
// k=(lane>>4)*8+j; C/D col=lane&15, row=(lane>>4)*4+reg).
// ---------------------------------------------------------------------------
__global__ __launch_bounds__(512, 4)
void attn_fwd_v11(const float* __restrict__ q_g, const char* __restrict__ kimg,
                  const char* __restrict__ vimg, const bf16x2* __restrict__ mt2_g,
                  float* __restrict__ o_g) {
  __shared__ __align__(16) char ldsK[2][16384];
  __shared__ __align__(16) char ldsV[2][16384];

  const int tid  = threadIdx.x;
  const int wid  = tid >> 6;            // 0..7
  const int lane = tid & 63;
  const int hi4  = lane >> 4;           // 0..3
  const int ql   = lane & 15;           // q-local / row-local

  // XCD swizzle: keep each bh's q-blocks on one XCD (K/V image L2 residency)
  const int lin = blockIdx.x;           // 0..1023
  const int xcd = lin & 7;
  const int idx = lin >> 3;             // 0..127
  const int bh  = xcd + 8 * (idx >> 4); // 0..63
  const int q0  = (idx & 15) * 128;

  const float* Qb = q_g + (size_t)bh * SEQ * HD;
  float*       Ob = o_g + (size_t)bh * SEQ * HD;

  const int qrow = q0 + wid * 16 + ql;

  // ---- Q fragments (B-operand): qf[kd][j] = Q[qrow][kd*32 + hi4*8 + j] ----
  bf16x8 qf[4];
#pragma unroll
  for (int kd = 0; kd < 4; ++kd) {
    const float* p = Qb + (size_t)qrow * HD + kd * 32 + hi4 * 8;
    float4 a = *(const float4*)p;
    float4 b = *(const float4*)(p + 4);
    qf[kd] = bf16x8{(bf16_t)a.x, (bf16_t)a.y, (bf16_t)a.z, (bf16_t)a.w,
                    (bf16_t)b.x, (bf16_t)b.y, (bf16_t)b.z, (bf16_t)b.w};
  }

  f32x4 ot[8];
#pragma unroll
  for (int dt = 0; dt < 8; ++dt) ot[dt] = f32x4{0.f, 0.f, 0.f, 0.f};
  f32x4 lsum = f32x4{0.f, 0.f, 0.f, 0.f};

  // per-wave DMA: 2KB of each 16KB image (8 waves cover the tile)
#define STAGE_K(T, BUF)                                                      \
  { const char* gK = kimg + ((size_t)bh * NT + (T)) * 16384 + wid * 2048 +   \
                     lane * 16;                                              \
    char* lK = ldsK[BUF] + wid * 2048;                                       \
    gl_lds16(gK, lK);                                                        \
    gl_lds16(gK + 1024, lK + 1024); }

#define STAGE_V(T, BUF)                                                      \
  { const char* gV = vimg + ((size_t)bh * NT + (T)) * 16384 + wid * 2048 +   \
                     lane * 16;                                              \
    char* lV = ldsV[BUF] + wid * 2048;                                       \
    gl_lds16(gV, lV);                                                        \
    gl_lds16(gV + 1024, lV + 1024); }

  // ---- prologue: DMA tile 0 (drains at the loop's first barrier) ----
  STAGE_K(0, 0)
  STAGE_V(0, 0)

  for (int t = 0; t < NT; ++t) {
    __syncthreads();                 // tile t DMA landed; old-buffer reads done
    const int buf = t & 1;
    const char* Kl = ldsK[buf];
    const char* Vl = ldsV[buf];
    const bool more = (t + 1 < NT);

    // packed mask: mreg[n16*4+r] = (M^T[k]*s, M^T[k+32]*s), k = n16*16+hi4*4+r
    bf16x2 mreg[8];
    {
      const bf16x2* MTp = mt2_g + (size_t)(t * 32) * SEQ + qrow;
#pragma unroll
      for (int n16 = 0; n16 < 2; ++n16)
#pragma unroll
        for (int r = 0; r < 4; ++r)
          mreg[n16 * 4 + r] = MTp[(size_t)(n16 * 16 + hi4 * 4 + r) * SEQ];
    }

    if (more) {
      STAGE_K(t + 1, buf ^ 1)        // ages across QK + softmax + PV
      STAGE_V(t + 1, buf ^ 1)
    }

    // ---- QK^T: S^T[k][q] as 4 16x16 tiles (k = n*16 + hi4*4 + reg) ----
    f32x4 sacc[4];
#pragma unroll
    for (int n = 0; n < 4; ++n) sacc[n] = f32x4{0.f, 0.f, 0.f, 0.f};
#pragma unroll
    for (int kd = 0; kd < 4; ++kd) {
#pragma unroll
      for (int n = 0; n < 4; ++n) {
        const int row = n * 16 + ql;                 // key row
        int byt = row * 256 + (kd * 32 + hi4 * 8) * 2;
        byt ^= (row & 7) << 4;
        bf16x8 kf = *(const bf16x8*)(Kl + byt);
        sacc[n] = __builtin_amdgcn_mfma_f32_16x16x32_bf16(kf, qf[kd], sacc[n], 0, 0, 0);
      }
    }

    // ---- softmax numerator (no max subtraction, no cross-lane) ----
    float p0[8], p1[8];
#pragma unroll
    for (int n16 = 0; n16 < 2; ++n16)
#pragma unroll
      for (int r = 0; r < 4; ++r) {
        const int i = n16 * 4 + r;
        p0[i] = __builtin_amdgcn_exp2f(
            fmaf(sacc[n16][r], SCALE_L2E, (float)mreg[i][0]));
        p1[i] = __builtin_amdgcn_exp2f(
            fmaf(sacc[n16 + 2][r], SCALE_L2E, (float)mreg[i][1]));
      }
#pragma unroll
    for (int r = 0; r < 4; ++r)
      lsum[r] += (p0[r] + p0[4 + r]) + (p1[r] + p1[4 + r]);

    // ---- P^T B-fragments: natural order (slot j = j2*4+j1 -> p[2m+j2][j1]) ----
    bf16x8 pf0 = bf16x8{(bf16_t)p0[0], (bf16_t)p0[1], (bf16_t)p0[2], (bf16_t)p0[3],
                        (bf16_t)p0[4], (bf16_t)p0[5], (bf16_t)p0[6], (bf16_t)p0[7]};
    bf16x8 pf1 = bf16x8{(bf16_t)p1[0], (bf16_t)p1[1], (bf16_t)p1[2], (bf16_t)p1[3],
                        (bf16_t)p1[4], (bf16_t)p1[5], (bf16_t)p1[6], (bf16_t)p1[7]};

    // ---- PV: O^T[d][q] += V^T · P^T, 16 16x16 MFMAs ----
#pragma unroll
    for (int m2 = 0; m2 < 2; ++m2) {
      const bf16x8 pf = m2 ? pf1 : pf0;
#pragma unroll
      for (int dt = 0; dt < 8; ++dt) {
        const int d = dt * 16 + ql;
        int byt = d * 128 + (m2 * 32 + hi4 * 8) * 2;
        byt ^= (d & 7) << 4;
        bf16x8 vf = *(const bf16x8*)(Vl + byt);
        ot[dt] = __builtin_amdgcn_mfma_f32_16x16x32_bf16(vf, pf, ot[dt], 0, 0, 0);
      }
    }
  }

  // ---- epilogue: l reduction (4 regs + 2 shuffles), O = O^T / l ----
  float l = (lsum[0] + lsum[1]) + (lsum[2] + lsum[3]);
  l += __shfl_xor(l, 16, 64);
  l += __shfl_xor(l, 32, 64);
  const float rinv = 1.f / l;

  float* Op = Ob + (size_t)qrow * HD;
#pragma unroll
  for (int dt = 0; dt < 8; ++dt) {
    const int d = dt * 16 + hi4 * 4;
    *(float4*)(Op + d) = float4{ot[dt][0] * rinv, ot[dt][1] * rinv,
                                ot[dt][2] * rinv, ot[dt][3] * rinv};
  }
}

extern "C" void kernel_launch(void* const* d_in, const int* in_sizes, int n_in,
                              void* d_out, int out_size, void* d_ws, size_t ws_size,
                              hipStream_t stream) {
  (void)in_sizes; (void)n_in; (void)out_size; (void)ws_size;
  const float* Q = (const float*)d_in[0];
  const float* K = (const float*)d_in[1];
  const float* V = (const float*)d_in[2];
  const float* M = (const float*)d_in[3];
  float*       O = (float*)d_out;

  const size_t szImg = (size_t)64 * NT * 16384;   // 33.55 MB per image
  char*   KI  = (char*)d_ws;
  char*   VI  = (char*)d_ws + szImg;
  bf16x2* MT2 = (bf16x2*)((char*)d_ws + 2 * szImg);   // 8.39 MB (ws >= 75.5 MB proven)

  prep_all<<<dim3(6144), 256, 0, stream>>>(K, V, M, KI, VI, MT2);
  attn_fwd_v11<<<dim3(1024), 512, 0, stream>>>(Q, KI, VI, MT2, O);
}